// Round 1
// baseline (384.110 us; speedup 1.0000x reference)
//
#include <hip/hip_runtime.h>

// NSVQ reference is degenerate: each stage i slices a single row
// flattened[i:i+1] / codebooks[i:i+1], so distances has one column,
// argmin == 0 always, and quantized == codebooks[i] broadcast to all tokens.
// => out[t,:] = codebooks[0] + codebooks[1] + codebooks[2] + codebooks[3]
// for every token t. Pure write-BW-bound broadcast of a 64-float vector.

#define N_TOKENS 1048576
#define EMB_DIM  64
// output as float4: 1048576 * 16
#define N_FLOAT4 (N_TOKENS * (EMB_DIM / 4))

__global__ __launch_bounds__(256) void nsvq_broadcast_kernel(
    const float* __restrict__ codebooks, float4* __restrict__ out4) {
  // Column group for this thread's float4 slots. Grid stride is a multiple
  // of 16 (blockDim=256), so (global index & 15) is invariant per thread.
  const int c = threadIdx.x & 15;

  const float4* __restrict__ cb4 = (const float4*)codebooks;
  // codebook row i starts at float4 index i*16
  float4 s0 = cb4[0 * 16 + c];
  float4 s1 = cb4[1 * 16 + c];
  float4 s2 = cb4[2 * 16 + c];
  float4 s3 = cb4[3 * 16 + c];

  // Match reference accumulation order: (((0 + cb0) + cb1) + cb2) + cb3
  float4 v;
  v.x = ((s0.x + s1.x) + s2.x) + s3.x;
  v.y = ((s0.y + s1.y) + s2.y) + s3.y;
  v.z = ((s0.z + s1.z) + s2.z) + s3.z;
  v.w = ((s0.w + s1.w) + s2.w) + s3.w;

  const int stride = gridDim.x * blockDim.x;  // multiple of 16
  for (int i = blockIdx.x * blockDim.x + threadIdx.x; i < N_FLOAT4; i += stride) {
    out4[i] = v;
  }
}

extern "C" void kernel_launch(void* const* d_in, const int* in_sizes, int n_in,
                              void* d_out, int out_size, void* d_ws, size_t ws_size,
                              hipStream_t stream) {
  (void)d_ws; (void)ws_size; (void)n_in; (void)in_sizes; (void)out_size;
  const float* codebooks = (const float*)d_in[1];  // d_in[0] (input_data) is unused by the math
  float4* out4 = (float4*)d_out;

  // 4096 blocks x 256 threads = 1M threads, 16 float4 stores each.
  nsvq_broadcast_kernel<<<4096, 256, 0, stream>>>(codebooks, out4);
}

// Round 3
// 377.991 us; speedup vs baseline: 1.0162x; 1.0162x over previous
//
#include <hip/hip_runtime.h>

// NSVQ reference is degenerate: each stage i slices a single row
// flattened[i:i+1] / codebooks[i:i+1], so distances has one column,
// argmin == 0 always, and quantized == codebooks[i] broadcast to all tokens.
// => out[t,:] = codebooks[0] + codebooks[1] + codebooks[2] + codebooks[3]
// for every token t. Pure write-BW-bound broadcast of a 64-float vector.
// Roofline: 256 MiB stores / ~6.6 TB/s ≈ 39 us.

#define N_TOKENS 1048576
#define EMB_DIM  64
#define N_FLOAT4 (N_TOKENS * (EMB_DIM / 4))   // 16,777,216 float4 stores
#define BLOCKS   4096
#define THREADS  256
#define PER_THREAD 16                          // N_FLOAT4 / (BLOCKS*THREADS)
#define BLOCK_SPAN (THREADS * PER_THREAD)      // 4096 float4 = 64 KiB per block

// Native vector type: __builtin_nontemporal_store rejects HIP_vector_type.
typedef float v4f __attribute__((ext_vector_type(4)));

__global__ __launch_bounds__(THREADS) void nsvq_broadcast_kernel(
    const float* __restrict__ codebooks, v4f* __restrict__ out4) {
  // Column group: block span (4096) and per-iter stride (256) are multiples
  // of 16, so (index & 15) == (threadIdx.x & 15) for every store this thread
  // makes — one 4-element sum covers all its stores.
  const int c = threadIdx.x & 15;

  const v4f* __restrict__ cb4 = (const v4f*)codebooks;
  v4f s0 = cb4[0 * 16 + c];
  v4f s1 = cb4[1 * 16 + c];
  v4f s2 = cb4[2 * 16 + c];
  v4f s3 = cb4[3 * 16 + c];

  // Match reference accumulation order: (((0 + cb0) + cb1) + cb2) + cb3
  v4f v = ((s0 + s1) + s2) + s3;

  // Block-contiguous: block b owns float4 indices [b*4096, (b+1)*4096).
  v4f* p = out4 + (size_t)blockIdx.x * BLOCK_SPAN + threadIdx.x;
#pragma unroll
  for (int j = 0; j < PER_THREAD; ++j) {
    // Streaming store: output is 8x L2 size and never re-read — bypass L2.
    __builtin_nontemporal_store(v, p + j * THREADS);
  }
}

extern "C" void kernel_launch(void* const* d_in, const int* in_sizes, int n_in,
                              void* d_out, int out_size, void* d_ws, size_t ws_size,
                              hipStream_t stream) {
  (void)d_ws; (void)ws_size; (void)n_in; (void)in_sizes; (void)out_size;
  const float* codebooks = (const float*)d_in[1];  // d_in[0] (input_data) unused by the math
  v4f* out4 = (v4f*)d_out;
  nsvq_broadcast_kernel<<<BLOCKS, THREADS, 0, stream>>>(codebooks, out4);
}